// Round 3
// baseline (147.866 us; speedup 1.0000x reference)
//
#include <hip/hip_runtime.h>
#include <hip/hip_bf16.h>

// TripletLoss batch-hard mining, B=8192, D=256.
// R3: symmetric Gram — only upper-triangle 256x256 block pairs (528 blocks),
//     each block updates row anchors (registers) AND col anchors (encoded
//     uint atomicMin/Max). Finish folded into last mine block. 2 launches.

constexpr int NB = 8192;
constexpr int ND = 256;
constexpr int TB = 256;               // block tile (rows and cols)
constexpr int BJ = 64;                // cols staged per iteration
constexpr int NITER = TB / BJ;        // 4
constexpr int NBLK = (NB / TB) * (NB / TB + 1) / 2;  // 528

typedef __attribute__((ext_vector_type(8))) short bf16x8;
typedef __attribute__((ext_vector_type(4))) float f32x4;

typedef __attribute__((address_space(3))) unsigned int lds_u32;
typedef __attribute__((address_space(1))) const unsigned int g_u32;

__device__ inline void load_lds16(const unsigned short* g, unsigned short* l) {
    __builtin_amdgcn_global_load_lds((g_u32*)g, (lds_u32*)l, 16, 0, 0);
}

__device__ inline unsigned short f2bf(float v) {
    __hip_bfloat16 b = __float2bfloat16(v);
    return *reinterpret_cast<unsigned short*>(&b);
}

// key = s + 8*min(|lr-lc|,1); pos keys in [-1,1], neg keys in [7,9].
// Encoded as uint bits of (key+2) in [1,11] > 0, so uint order == float order.
// min(enc) over all j = hardest positive; max(enc) = hardest negative.
// ENC6 = bits of 6.0f separates pos (<6) from neg (>6).
#define ENC6 0x40C00000u

// ---------------- Kernel 1: normalize rows -> bf16 chunk-major; init state --
__global__ __launch_bounds__(256) void norm_kernel(const float* __restrict__ X,
                                                   unsigned short* __restrict__ Xbt,
                                                   unsigned int* minKey,
                                                   unsigned int* maxKey, int* done) {
    __shared__ float tile[32][260];
    __shared__ float psum[32][8];
    __shared__ float rscale[32];
    const int t = threadIdx.x;
    const int rb = blockIdx.x * 32;
    const int g = blockIdx.x * 256 + t;
    if (g < NB) { minKey[g] = 0xFFFFFFFFu; maxKey[g] = 0u; }
    if (g == 0) *done = 0;
    #pragma unroll
    for (int k = 0; k < 8; k++) {
        const int f = k * 256 + t;
        const int row = f >> 6, c4 = f & 63;
        const float4 v = *((const float4*)(X + (size_t)(rb + row) * ND) + c4);
        *(float4*)&tile[row][c4 * 4] = v;
    }
    __syncthreads();
    {
        const int r = t >> 3, e = t & 7;
        float s = 0.f;
        #pragma unroll
        for (int i = 0; i < 32; i++) { const float v = tile[r][e * 32 + i]; s += v * v; }
        psum[r][e] = s;
    }
    __syncthreads();
    if (t < 32) {
        float s = 0.f;
        #pragma unroll
        for (int e = 0; e < 8; e++) s += psum[t][e];
        rscale[t] = 1.0f / fmaxf(sqrtf(s), 1e-12f);
    }
    __syncthreads();
    #pragma unroll
    for (int j = 0; j < 4; j++) {
        const int idx = j * 256 + t;
        const int q = idx >> 5, r = idx & 31;
        const float sc = rscale[r];
        unsigned short tmp[8];
        #pragma unroll
        for (int e = 0; e < 8; e++) tmp[e] = f2bf(tile[r][q * 8 + e] * sc);
        *(bf16x8*)(Xbt + ((size_t)q * NB + rb + r) * 8) = *(bf16x8*)tmp;
    }
}

// ---------------- Kernel 2: symmetric Gram + mining + folded finish ---------
__global__ __launch_bounds__(256, 2) void mine_kernel(
    const unsigned short* __restrict__ Xbt, const int* __restrict__ labels,
    unsigned int* minKey, unsigned int* maxKey, int* done,
    float* __restrict__ out) {
    __shared__ unsigned short Bt[32 * 512];   // 32 KB
    __shared__ float Ljf[BJ];
    __shared__ int ticket_s;

    // triangle decode: t -> (a,b), b<=a; rows=b, cols=a
    {   }
    const int tb = blockIdx.x;
    int a = (int)((sqrtf(8.0f * (float)tb + 1.0f) - 1.0f) * 0.5f);
    while ((a + 1) * (a + 2) / 2 <= tb) a++;
    while (a * (a + 1) / 2 > tb) a--;
    const int Iblk = tb - a * (a + 1) / 2;    // row block (<= a)
    const int Jblk = a;                       // col block
    const bool isdiag = (Iblk == Jblk);

    const int tid = threadIdx.x;
    const int w = tid >> 6;
    const int lane = tid & 63;
    const int quad = lane >> 4;
    const int l16 = lane & 15;

    const int rowbase = Iblk * TB + w * 64;

    bf16x8 afrag[4][8];
    #pragma unroll
    for (int rs = 0; rs < 4; rs++)
        #pragma unroll
        for (int kc = 0; kc < 8; kc++) {
            const size_t u = (size_t)(kc * 4 + quad) * NB + (rowbase + rs * 16 + l16);
            afrag[rs][kc] = *(const bf16x8*)(Xbt + u * 8);
        }

    float flr[4][4], minK[4][4], maxK[4][4];
    #pragma unroll
    for (int rs = 0; rs < 4; rs++)
        #pragma unroll
        for (int r = 0; r < 4; r++) {
            flr[rs][r] = (float)labels[rowbase + rs * 16 + quad * 4 + r];
            minK[rs][r] = 1e30f;
            maxK[rs][r] = -1e30f;
        }

    for (int jt = 0; jt < NITER; jt++) {
        const int jbase = Jblk * TB + jt * BJ;
        __syncthreads();
        #pragma unroll
        for (int s = 0; s < 8; s++) {
            const int rg = w * 8 + s;
            const int kc = rg >> 2, nfi = rg & 3;
            const size_t u = (size_t)(kc * 4 + quad) * NB + (jbase + nfi * 16 + l16);
            load_lds16(Xbt + u * 8, Bt + rg * 512);
        }
        if (tid < BJ) Ljf[tid] = (float)labels[jbase + tid];
        __syncthreads();

        #pragma unroll
        for (int nf = 0; nf < 4; nf++) {
            const float flc = Ljf[nf * 16 + l16];
            f32x4 acc[4];
            #pragma unroll
            for (int rs = 0; rs < 4; rs++) acc[rs] = (f32x4){0.f, 0.f, 0.f, 0.f};
            #pragma unroll
            for (int kc = 0; kc < 8; kc++) {
                const bf16x8 b = *(const bf16x8*)(Bt + (kc * 4 + nf) * 512 + lane * 8);
                #pragma unroll
                for (int rs = 0; rs < 4; rs++)
                    acc[rs] = __builtin_amdgcn_mfma_f32_16x16x32_bf16(
                        afrag[rs][kc], b, acc[rs], 0, 0, 0);
            }
            float cMin = 1e30f, cMax = -1e30f;
            #pragma unroll
            for (int rs = 0; rs < 4; rs++)
                #pragma unroll
                for (int r = 0; r < 4; r++) {
                    const float d = flr[rs][r] - flc;
                    const float uu = fminf(fabsf(d), 1.0f);
                    const float key = fmaf(uu, 8.0f, acc[rs][r]);
                    minK[rs][r] = fminf(minK[rs][r], key);
                    maxK[rs][r] = fmaxf(maxK[rs][r], key);
                    cMin = fminf(cMin, key);
                    cMax = fmaxf(cMax, key);
                }
            if (!isdiag) {  // col-side updates (rows I-range -> anchors J-range)
                cMin = fminf(cMin, __shfl_xor(cMin, 16, 64));
                cMin = fminf(cMin, __shfl_xor(cMin, 32, 64));
                cMax = fmaxf(cMax, __shfl_xor(cMax, 16, 64));
                cMax = fmaxf(cMax, __shfl_xor(cMax, 32, 64));
                if (quad == 0) {
                    const int col = jbase + nf * 16 + l16;
                    atomicMin(&minKey[col], __float_as_uint(cMin + 2.0f));
                    atomicMax(&maxKey[col], __float_as_uint(cMax + 2.0f));
                }
            }
        }
    }

    // row-side: reduce over the 16 lanes sharing each row, then atomics
    #pragma unroll
    for (int rs = 0; rs < 4; rs++)
        #pragma unroll
        for (int r = 0; r < 4; r++) {
            float p = minK[rs][r], n = maxK[rs][r];
            #pragma unroll
            for (int m = 1; m <= 8; m <<= 1) {
                p = fminf(p, __shfl_xor(p, m, 64));
                n = fmaxf(n, __shfl_xor(n, m, 64));
            }
            if (l16 == 0) {
                const int row = rowbase + rs * 16 + quad * 4 + r;
                atomicMin(&minKey[row], __float_as_uint(p + 2.0f));
                atomicMax(&maxKey[row], __float_as_uint(n + 2.0f));
            }
        }

    // folded finish: last block to arrive reduces the key arrays
    __threadfence();
    __syncthreads();
    if (tid == 0) ticket_s = atomicAdd(done, 1);
    __syncthreads();
    if (ticket_s == (int)gridDim.x - 1) {
        __threadfence();
        float per = 0.f, cnt = 0.f;
        #pragma unroll
        for (int k = 0; k < NB / 256; k++) {
            const int i = k * 256 + tid;
            const unsigned int mk = minKey[i], xk = maxKey[i];
            const bool valid = (mk < ENC6) && (xk > ENC6);
            const float ps = __uint_as_float(mk) - 2.0f;   // hardest-pos sim
            const float ns = __uint_as_float(xk) - 10.0f;  // hardest-neg sim
            const float pd = fmaxf(1.0f - ps, 0.0f);
            const float nd = fmaxf(1.0f - ns, 0.0f);
            per += valid ? fmaxf(pd - nd + 1.0f, 0.0f) : 0.0f;
            cnt += valid ? 1.0f : 0.0f;
        }
        #pragma unroll
        for (int off = 32; off > 0; off >>= 1) {
            per += __shfl_down(per, off, 64);
            cnt += __shfl_down(cnt, off, 64);
        }
        __shared__ float sp[4], sc[4];
        const int wv = tid >> 6, ln = tid & 63;
        if (ln == 0) { sp[wv] = per; sc[wv] = cnt; }
        __syncthreads();
        if (tid == 0) {
            const float s = sp[0] + sp[1] + sp[2] + sp[3];
            const float c = sc[0] + sc[1] + sc[2] + sc[3];
            out[0] = (c > 0.f) ? s / fmaxf(c, 1.f) : 0.f;
        }
    }
}

// ---------------- launcher --------------------------------------------------
extern "C" void kernel_launch(void* const* d_in, const int* in_sizes, int n_in,
                              void* d_out, int out_size, void* d_ws, size_t ws_size,
                              hipStream_t stream) {
    const float* X = (const float*)d_in[0];
    const int* labels = (const int*)d_in[1];
    float* out = (float*)d_out;

    char* ws = (char*)d_ws;
    unsigned short* Xbt = (unsigned short*)ws;                    // 4 MB
    unsigned int* minKey = (unsigned int*)(ws + (size_t)4 * 1024 * 1024);
    unsigned int* maxKey = minKey + NB;
    int* done = (int*)(maxKey + NB);

    norm_kernel<<<NB / 32, 256, 0, stream>>>(X, Xbt, minKey, maxKey, done);
    mine_kernel<<<NBLK, 256, 0, stream>>>(
        (const unsigned short*)Xbt, labels, minKey, maxKey, done, out);
}

// Round 4
// 145.312 us; speedup vs baseline: 1.0176x; 1.0176x over previous
//
#include <hip/hip_runtime.h>
#include <hip/hip_bf16.h>

// TripletLoss batch-hard mining, B=8192, D=256.
// R4: R3's symmetric-triangle algorithm, but WITHOUT the launch_bounds VGPR
//     cap that forced ~230 live regs into a 128-reg budget (scratch spill,
//     WRITE_SIZE 19.8MB, 94us). __launch_bounds__(256,1) -> ~230 VGPRs fits
//     the <=256 bucket = 2 waves/SIMD = 2 blocks/CU (LDS 2x32.5KB ok).

constexpr int NB = 8192;
constexpr int ND = 256;
constexpr int TB = 256;               // block tile (rows and cols)
constexpr int BJ = 64;                // cols staged per iteration
constexpr int NITER = TB / BJ;        // 4
constexpr int NBLK = (NB / TB) * (NB / TB + 1) / 2;  // 528

typedef __attribute__((ext_vector_type(8))) short bf16x8;
typedef __attribute__((ext_vector_type(4))) float f32x4;

typedef __attribute__((address_space(3))) unsigned int lds_u32;
typedef __attribute__((address_space(1))) const unsigned int g_u32;

__device__ inline void load_lds16(const unsigned short* g, unsigned short* l) {
    __builtin_amdgcn_global_load_lds((g_u32*)g, (lds_u32*)l, 16, 0, 0);
}

__device__ inline unsigned short f2bf(float v) {
    __hip_bfloat16 b = __float2bfloat16(v);
    return *reinterpret_cast<unsigned short*>(&b);
}

// key = s + 8*min(|lr-lc|,1); pos keys in [-1,1], neg keys in [7,9].
// Encoded as uint bits of (key+2) in [1,11] > 0, so uint order == float order.
// min(enc) = hardest positive; max(enc) = hardest negative. ENC6 = bits of 6.0f.
#define ENC6 0x40C00000u

// ---------------- Kernel 1: normalize rows -> bf16 chunk-major; init state --
__global__ __launch_bounds__(256) void norm_kernel(const float* __restrict__ X,
                                                   unsigned short* __restrict__ Xbt,
                                                   unsigned int* minKey,
                                                   unsigned int* maxKey, int* done) {
    __shared__ float tile[32][260];
    __shared__ float psum[32][8];
    __shared__ float rscale[32];
    const int t = threadIdx.x;
    const int rb = blockIdx.x * 32;
    const int g = blockIdx.x * 256 + t;
    if (g < NB) { minKey[g] = 0xFFFFFFFFu; maxKey[g] = 0u; }
    if (g == 0) *done = 0;
    #pragma unroll
    for (int k = 0; k < 8; k++) {
        const int f = k * 256 + t;
        const int row = f >> 6, c4 = f & 63;
        const float4 v = *((const float4*)(X + (size_t)(rb + row) * ND) + c4);
        *(float4*)&tile[row][c4 * 4] = v;
    }
    __syncthreads();
    {
        const int r = t >> 3, e = t & 7;
        float s = 0.f;
        #pragma unroll
        for (int i = 0; i < 32; i++) { const float v = tile[r][e * 32 + i]; s += v * v; }
        psum[r][e] = s;
    }
    __syncthreads();
    if (t < 32) {
        float s = 0.f;
        #pragma unroll
        for (int e = 0; e < 8; e++) s += psum[t][e];
        rscale[t] = 1.0f / fmaxf(sqrtf(s), 1e-12f);
    }
    __syncthreads();
    #pragma unroll
    for (int j = 0; j < 4; j++) {
        const int idx = j * 256 + t;
        const int q = idx >> 5, r = idx & 31;
        const float sc = rscale[r];
        unsigned short tmp[8];
        #pragma unroll
        for (int e = 0; e < 8; e++) tmp[e] = f2bf(tile[r][q * 8 + e] * sc);
        *(bf16x8*)(Xbt + ((size_t)q * NB + rb + r) * 8) = *(bf16x8*)tmp;
    }
}

// ---------------- Kernel 2: symmetric Gram + mining + folded finish ---------
__global__ __launch_bounds__(256, 1) void mine_kernel(
    const unsigned short* __restrict__ Xbt, const int* __restrict__ labels,
    unsigned int* minKey, unsigned int* maxKey, int* done,
    float* __restrict__ out) {
    __shared__ unsigned short Bt[32 * 512];   // 32 KB
    __shared__ float Ljf[TB];
    __shared__ int ticket_s;

    // triangle decode: blockIdx.x -> (Jblk=a, Iblk<=a)
    const int tb = blockIdx.x;
    int a = (int)((sqrtf(8.0f * (float)tb + 1.0f) - 1.0f) * 0.5f);
    while ((a + 1) * (a + 2) / 2 <= tb) a++;
    while (a * (a + 1) / 2 > tb) a--;
    const int Iblk = tb - a * (a + 1) / 2;
    const int Jblk = a;
    const bool isdiag = (Iblk == Jblk);

    const int tid = threadIdx.x;
    const int w = tid >> 6;
    const int lane = tid & 63;
    const int quad = lane >> 4;
    const int l16 = lane & 15;

    const int rowbase = Iblk * TB + w * 64;

    // col labels once per block
    Ljf[tid] = (float)labels[Jblk * TB + tid];

    bf16x8 afrag[4][8];
    #pragma unroll
    for (int rs = 0; rs < 4; rs++)
        #pragma unroll
        for (int kc = 0; kc < 8; kc++) {
            const size_t u = (size_t)(kc * 4 + quad) * NB + (rowbase + rs * 16 + l16);
            afrag[rs][kc] = *(const bf16x8*)(Xbt + u * 8);
        }

    float flr[4][4], minK[4][4], maxK[4][4];
    #pragma unroll
    for (int rs = 0; rs < 4; rs++)
        #pragma unroll
        for (int r = 0; r < 4; r++) {
            flr[rs][r] = (float)labels[rowbase + rs * 16 + quad * 4 + r];
            minK[rs][r] = 1e30f;
            maxK[rs][r] = -1e30f;
        }

    for (int jt = 0; jt < NITER; jt++) {
        const int jbase = Jblk * TB + jt * BJ;
        __syncthreads();  // protect Bt (and order Ljf on first iter)
        #pragma unroll
        for (int s = 0; s < 8; s++) {
            const int rg = w * 8 + s;
            const int kc = rg >> 2, nfi = rg & 3;
            const size_t u = (size_t)(kc * 4 + quad) * NB + (jbase + nfi * 16 + l16);
            load_lds16(Xbt + u * 8, Bt + rg * 512);
        }
        __syncthreads();  // drains vmcnt incl. global_load_lds

        #pragma unroll
        for (int nf = 0; nf < 4; nf++) {
            const float flc = Ljf[jt * BJ + nf * 16 + l16];
            f32x4 acc[4];
            #pragma unroll
            for (int rs = 0; rs < 4; rs++) acc[rs] = (f32x4){0.f, 0.f, 0.f, 0.f};
            #pragma unroll
            for (int kc = 0; kc < 8; kc++) {
                const bf16x8 b = *(const bf16x8*)(Bt + (kc * 4 + nf) * 512 + lane * 8);
                #pragma unroll
                for (int rs = 0; rs < 4; rs++)
                    acc[rs] = __builtin_amdgcn_mfma_f32_16x16x32_bf16(
                        afrag[rs][kc], b, acc[rs], 0, 0, 0);
            }
            float cMin = 1e30f, cMax = -1e30f;
            #pragma unroll
            for (int rs = 0; rs < 4; rs++)
                #pragma unroll
                for (int r = 0; r < 4; r++) {
                    const float d = flr[rs][r] - flc;
                    const float uu = fminf(fabsf(d), 1.0f);
                    const float key = fmaf(uu, 8.0f, acc[rs][r]);
                    minK[rs][r] = fminf(minK[rs][r], key);
                    maxK[rs][r] = fmaxf(maxK[rs][r], key);
                    cMin = fminf(cMin, key);
                    cMax = fmaxf(cMax, key);
                }
            if (!isdiag) {  // col-side updates (anchors in J-range)
                cMin = fminf(cMin, __shfl_xor(cMin, 16, 64));
                cMin = fminf(cMin, __shfl_xor(cMin, 32, 64));
                cMax = fmaxf(cMax, __shfl_xor(cMax, 16, 64));
                cMax = fmaxf(cMax, __shfl_xor(cMax, 32, 64));
                if (quad == 0) {
                    const int col = jbase + nf * 16 + l16;
                    atomicMin(&minKey[col], __float_as_uint(cMin + 2.0f));
                    atomicMax(&maxKey[col], __float_as_uint(cMax + 2.0f));
                }
            }
        }
    }

    // row-side: reduce over the 16 lanes sharing each row, then atomics
    #pragma unroll
    for (int rs = 0; rs < 4; rs++)
        #pragma unroll
        for (int r = 0; r < 4; r++) {
            float p = minK[rs][r], n = maxK[rs][r];
            #pragma unroll
            for (int m = 1; m <= 8; m <<= 1) {
                p = fminf(p, __shfl_xor(p, m, 64));
                n = fmaxf(n, __shfl_xor(n, m, 64));
            }
            if (l16 == 0) {
                const int row = rowbase + rs * 16 + quad * 4 + r;
                atomicMin(&minKey[row], __float_as_uint(p + 2.0f));
                atomicMax(&maxKey[row], __float_as_uint(n + 2.0f));
            }
        }

    // folded finish: last block to arrive reduces the key arrays
    __threadfence();
    __syncthreads();
    if (tid == 0) ticket_s = atomicAdd(done, 1);
    __syncthreads();
    if (ticket_s == (int)gridDim.x - 1) {
        __threadfence();
        float per = 0.f, cnt = 0.f;
        #pragma unroll
        for (int k = 0; k < NB / 256; k++) {
            const int i = k * 256 + tid;
            const unsigned int mk = minKey[i], xk = maxKey[i];
            const bool valid = (mk < ENC6) && (xk > ENC6);
            const float ps = __uint_as_float(mk) - 2.0f;   // hardest-pos sim
            const float ns = __uint_as_float(xk) - 10.0f;  // hardest-neg sim
            const float pd = fmaxf(1.0f - ps, 0.0f);
            const float nd = fmaxf(1.0f - ns, 0.0f);
            per += valid ? fmaxf(pd - nd + 1.0f, 0.0f) : 0.0f;
            cnt += valid ? 1.0f : 0.0f;
        }
        #pragma unroll
        for (int off = 32; off > 0; off >>= 1) {
            per += __shfl_down(per, off, 64);
            cnt += __shfl_down(cnt, off, 64);
        }
        __shared__ float sp[4], sc[4];
        const int wv = tid >> 6, ln = tid & 63;
        if (ln == 0) { sp[wv] = per; sc[wv] = cnt; }
        __syncthreads();
        if (tid == 0) {
            const float s = sp[0] + sp[1] + sp[2] + sp[3];
            const float c = sc[0] + sc[1] + sc[2] + sc[3];
            out[0] = (c > 0.f) ? s / fmaxf(c, 1.f) : 0.f;
        }
    }
}

// ---------------- launcher --------------------------------------------------
extern "C" void kernel_launch(void* const* d_in, const int* in_sizes, int n_in,
                              void* d_out, int out_size, void* d_ws, size_t ws_size,
                              hipStream_t stream) {
    const float* X = (const float*)d_in[0];
    const int* labels = (const int*)d_in[1];
    float* out = (float*)d_out;

    char* ws = (char*)d_ws;
    unsigned short* Xbt = (unsigned short*)ws;                    // 4 MB
    unsigned int* minKey = (unsigned int*)(ws + (size_t)4 * 1024 * 1024);
    unsigned int* maxKey = minKey + NB;
    int* done = (int*)(maxKey + NB);

    norm_kernel<<<NB / 32, 256, 0, stream>>>(X, Xbt, minKey, maxKey, done);
    mine_kernel<<<NBLK, 256, 0, stream>>>(
        (const unsigned short*)Xbt, labels, minKey, maxKey, done, out);
}